// Round 3
// baseline (177.117 us; speedup 1.0000x reference)
//
#include <hip/hip_runtime.h>

typedef __attribute__((ext_vector_type(8))) short bf16x8;
typedef __attribute__((ext_vector_type(4))) float f32x4;
typedef __attribute__((ext_vector_type(4))) unsigned short u16x4;
typedef __attribute__((ext_vector_type(8))) unsigned short u16x8;

#define B_ 2048
#define A_ 50
#define H_ 512
#define NACT_ 64
#define F_ 562
#define BM_ 64
#define BK_ 32
#define NSTEP_ (H_ / BK_) /* 16 */
#define AH_ (A_ * H_)     /* x row stride in floats */

// ws layout (bytes)
#define WS_W1T 0
#define WS_W2T ((size_t)A_ * H_ * H_ * 2)                    /* 26,214,400 */
#define WS_B1 (WS_W2T + (size_t)A_ * NACT_ * H_ * 2)         /* 29,491,200 */
#define WS_B2 (WS_B1 + (size_t)A_ * H_ * 4)                  /* 29,593,600 */

static __device__ __forceinline__ unsigned short f2bf(float f) {
  unsigned int u = __builtin_bit_cast(unsigned int, f);
  u += 0x7fffu + ((u >> 16) & 1u);
  return (unsigned short)(u >> 16);
}

static __device__ __forceinline__ void gld_lds16(const unsigned short* src,
                                                 unsigned short* dst) {
  __builtin_amdgcn_global_load_lds(
      (const __attribute__((address_space(1))) unsigned int*)(const void*)src,
      (__attribute__((address_space(3))) unsigned int*)(void*)dst, 16, 0, 0);
}

static __device__ __forceinline__ int clamp_r(int r) {
  return r < 0 ? 0 : (r > A_ - 1 ? A_ - 1 : r);
}

// W1T step-tiled + pre-swizzled (unchanged layout, coalesced u16x8 stores):
// value (a,j,k), t=k>>5, sub=(k>>3)&3, elem=k&7 stored at
//   ((a*16 + t)*512 + j)*32 + (sub ^ (j&3))*8 + elem
__global__ void prep_w1(const float* __restrict__ w1,
                        const int* __restrict__ routing,
                        unsigned short* __restrict__ w1t) {
  const int bid = blockIdx.x;
  const int a = bid / 64;
  const int tile = bid - a * 64;
  const int tk = tile & 7, tj = tile >> 3;
  const int k0 = tk * 64, j0 = tj * 64;
  const int r = clamp_r(routing[a]);
  __shared__ float tl[64][65];
  const int t = threadIdx.x;
  const int c = t & 63, q = t >> 6;
#pragma unroll
  for (int i = 0; i < 16; ++i) {
    const int kl = q + i * 4;
    tl[kl][c] = w1[((size_t)r * F_ + k0 + kl) * H_ + j0 + c];
  }
  __syncthreads();
  // phase 2: 512 items (64 j x 8 k-chunks), 16B stores
#pragma unroll
  for (int it = 0; it < 2; ++it) {
    const int item = it * 256 + t;
    const int jl = item >> 3, kc = item & 7;
    const int j = j0 + jl;
    const int ts = (k0 + kc * 8) >> 5;
    u16x8 v;
#pragma unroll
    for (int e = 0; e < 8; ++e) v[e] = f2bf(tl[kc * 8 + e][jl]);
    unsigned short* dst = w1t + (((size_t)a * 16 + ts) * H_ + j) * 32 +
                          (size_t)(((kc & 3) ^ (j & 3)) << 3);
    *(u16x8*)dst = v;
  }
}

// W2T[a][n][k] = bf16(W2[r_a][k][n])
__global__ void prep_w2(const float* __restrict__ w2,
                        const int* __restrict__ routing,
                        unsigned short* __restrict__ w2t) {
  const int bid = blockIdx.x;
  const int a = bid >> 3;
  const int tk = bid & 7;
  const int k0 = tk * 64;
  const int r = clamp_r(routing[a]);
  __shared__ float tl[64][65];
  const int t = threadIdx.x;
  const int c = t & 63, q = t >> 6;
#pragma unroll
  for (int i = 0; i < 16; ++i) {
    const int kl = q + i * 4;
    tl[kl][c] = w2[((size_t)r * H_ + k0 + kl) * NACT_ + c];
  }
  __syncthreads();
#pragma unroll
  for (int i = 0; i < 16; ++i) {
    const int nl = q + i * 4;
    w2t[((size_t)a * NACT_ + nl) * H_ + k0 + c] = f2bf(tl[c][nl]);
  }
}

__global__ void prep_bias(const float* __restrict__ w1,
                          const float* __restrict__ b1,
                          const float* __restrict__ b2,
                          const int* __restrict__ routing,
                          float* __restrict__ bias1, float* __restrict__ bias2) {
  const int a = blockIdx.x;
  const int t = threadIdx.x;
  const int r = clamp_r(routing[a]);
  bias1[a * H_ + t] = b1[(size_t)r * H_ + t] + w1[((size_t)r * F_ + H_ + a) * H_ + t];
  if (t < NACT_) bias2[a * NACT_ + t] = b2[r * NACT_ + t];
}

__global__ __launch_bounds__(512, 2) void divtree_main(
    const float* __restrict__ x, const unsigned short* __restrict__ w1t,
    const unsigned short* __restrict__ w2t, const float* __restrict__ bias1,
    const float* __restrict__ bias2, float* __restrict__ out) {
  __shared__ union {
    struct {
      unsigned short w1[2][H_ * BK_];   // 2 x 32 KiB, linear (pre-swizzled)
      unsigned short xs[2][BM_ * BK_];  // 2 x 4 KiB, swizzled rows
    } st;                               // 72 KiB
    unsigned short h[BM_ * H_];         // 64 KiB (after K-loop)
    float outb[BM_][66];                // 16.9 KiB (after layer 2)
  } sm;

  // XCD-bijective swizzle: 1600 blocks, 1600 % 8 == 0 -> cpx = 200
  const int bid = blockIdx.x;
  const int swz = (bid & 7) * 200 + (bid >> 3);
  const int a = swz >> 5;    // agent (0..49)
  const int mblk = swz & 31; // M tile (0..31)
  const int b0 = mblk * BM_;

  const int tid = threadIdx.x;
  const int lane = tid & 63;
  const int w = tid >> 6; // wave 0..7
  const int l16 = lane & 15;
  const int lk = lane >> 4; // 0..3
  const int sxor = lk ^ (l16 & 3); // fragment-read chunk XOR

  // layer-1 wave tile: 64(j) x 64(m); 8 waves cover j=512
  const int wj = w * 64;

  const unsigned short* w1ta = w1t + (size_t)a * (H_ * H_);

  // ---- x burst mapping (DRAM page locality) ----
  // Wave w owns rows w*8 .. w*8+7. Per burst (4 K-steps = 512B/row):
  //   instr i (0..3): lane (r2=lane>>5, c=lane&31) reads f32x4 of row
  //   w*8 + 2i + r2 at float offset tb*32 + c*4  -> 2 rows x 512B
  //   contiguous per instruction, 4 sequential 128B lines per page.
  const int r2 = lane >> 5;
  const int cc = lane & 31;      // 16B chunk within 512B burst range
  const int xq = cc & 7;         // 4-float chunk within a K-step
  const int xact = cc >> 3;      // which step-of-burst this lane holds
  const float* xpt =
      x + ((size_t)(b0 + (w << 3) + r2) * A_ + (size_t)a) * H_ + (size_t)cc * 4;
  // xs write offsets for the 4 rows this lane covers (swizzled layout)
  int xs_off[4];
#pragma unroll
  for (int i = 0; i < 4; ++i) {
    const int row = (w << 3) + 2 * i + r2;
    xs_off[i] = row * BK_ + ((xq >> 1) ^ (row & 3)) * 8 + (xq & 1) * 4;
  }

  // fragment LDS offsets (ushort units)
  const int afr_base = (wj + l16) * BK_ + sxor * 8;
  const int bfr_base = l16 * BK_ + sxor * 8;

  f32x4 acc[4][4];
#pragma unroll
  for (int i = 0; i < 4; ++i)
#pragma unroll
    for (int j = 0; j < 4; ++j) acc[i][j] = (f32x4){0.f, 0.f, 0.f, 0.f};

  f32x4 xr[4];
  u16x4 xbf[4];

  // prologue: burst 0 (steps 0..3) + W1 step-0 stage + xs step-0 write
  {
#pragma unroll
    for (int i = 0; i < 4; ++i)
      xr[i] = *(const f32x4*)(xpt + (size_t)(2 * i) * AH_);
#pragma unroll
    for (int i = 0; i < 4; ++i)
      gld_lds16(w1ta + ((size_t)(i * 512 + tid) << 3),
                sm.st.w1[0] + (size_t)(i * 512 + (w << 6)) * 8);
#pragma unroll
    for (int i = 0; i < 4; ++i)
#pragma unroll
      for (int e = 0; e < 4; ++e) xbf[i][e] = f2bf(xr[i][e]);
    if (xact == 0) {
#pragma unroll
      for (int i = 0; i < 4; ++i) *(u16x4*)(sm.st.xs[0] + xs_off[i]) = xbf[i];
    }
  }
  __syncthreads();

#pragma unroll
  for (int t = 0; t < NSTEP_; ++t) {
    const int buf = t & 1;
    const bool pf = (t + 1 < NSTEP_);
    if (((t & 3) == 3) && pf) { // issue x burst for steps t+1..t+4
      const float* p = xpt + (size_t)(t + 1) * BK_;
#pragma unroll
      for (int i = 0; i < 4; ++i)
        xr[i] = *(const f32x4*)(p + (size_t)(2 * i) * AH_);
    }
    if (pf) { // W1 prefetch for t+1
      const unsigned short* wsrc = w1ta + (size_t)(t + 1) * (H_ * BK_);
#pragma unroll
      for (int i = 0; i < 4; ++i)
        gld_lds16(wsrc + ((size_t)(i * 512 + tid) << 3),
                  sm.st.w1[buf ^ 1] + (size_t)(i * 512 + (w << 6)) * 8);
    }
    // compute current tile: D[j][m] = W1T(j,k) * x(m,k)^T
    {
      const unsigned short* w1s = sm.st.w1[buf];
      const unsigned short* xss = sm.st.xs[buf];
      bf16x8 bfr[4];
#pragma unroll
      for (int mf = 0; mf < 4; ++mf)
        bfr[mf] = *(const bf16x8*)(xss + bfr_base + mf * (16 * BK_));
#pragma unroll
      for (int jf = 0; jf < 4; ++jf) {
        const bf16x8 afr = *(const bf16x8*)(w1s + afr_base + jf * (16 * BK_));
#pragma unroll
        for (int mf = 0; mf < 4; ++mf)
          acc[jf][mf] = __builtin_amdgcn_mfma_f32_16x16x32_bf16(
              afr, bfr[mf], acc[jf][mf], 0, 0, 0);
      }
    }
    if (((t & 3) == 3) && pf) { // convert arrived burst to bf16
#pragma unroll
      for (int i = 0; i < 4; ++i)
#pragma unroll
        for (int e = 0; e < 4; ++e) xbf[i][e] = f2bf(xr[i][e]);
    }
    if (pf && xact == ((t + 1) & 3)) { // write xs slice for step t+1
#pragma unroll
      for (int i = 0; i < 4; ++i)
        *(u16x4*)(sm.st.xs[buf ^ 1] + xs_off[i]) = xbf[i];
    }
    __syncthreads();
  }

  // h = relu(acc + bias1_eff) -> LDS bf16, XOR-swizzled rows
  const float* b1p = bias1 + a * H_;
#pragma unroll
  for (int jf = 0; jf < 4; ++jf) {
    const f32x4 bv = *(const f32x4*)(b1p + wj + jf * 16 + lk * 4);
    const int cbase = (wj >> 3) + jf * 2 + (lk >> 1);
    const int half4 = (lk & 1) * 4;
#pragma unroll
    for (int mf = 0; mf < 4; ++mf) {
      u16x4 hv;
#pragma unroll
      for (int r = 0; r < 4; ++r) {
        float f = acc[jf][mf][r] + bv[r];
        f = f > 0.f ? f : 0.f;
        hv[r] = f2bf(f);
      }
      const int m = mf * 16 + l16;
      const int off = m * H_ + ((cbase ^ (l16 & 7))) * 8 + half4;
      *(u16x4*)(sm.h + off) = hv;
    }
  }
  __syncthreads();

  // layer 2: out[m][n] = h(m,k) * W2T(n,k)^T ; wave tile 32(m) x 16(n)
  const int m0 = (w & 1) * 32;
  const int n0 = (w >> 1) * 16;
  const unsigned short* w2p =
      w2t + ((size_t)a * NACT_ + n0 + l16) * H_ + lk * 8;
  f32x4 acc2[2];
  acc2[0] = (f32x4){0.f, 0.f, 0.f, 0.f};
  acc2[1] = (f32x4){0.f, 0.f, 0.f, 0.f};
#pragma unroll
  for (int kf = 0; kf < 16; ++kf) {
    const bf16x8 bf2 = *(const bf16x8*)(w2p + kf * 32);
#pragma unroll
    for (int mf = 0; mf < 2; ++mf) {
      const int row = m0 + mf * 16 + l16;
      const int off = row * H_ + (((kf * 4 + lk) ^ (l16 & 7))) * 8;
      const bf16x8 af2 = *(const bf16x8*)(sm.h + off);
      acc2[mf] = __builtin_amdgcn_mfma_f32_16x16x32_bf16(af2, bf2, acc2[mf],
                                                         0, 0, 0);
    }
  }
  const float b2v = bias2[a * NACT_ + n0 + l16];
  __syncthreads(); // h reads done before outb overwrite (aliased)
#pragma unroll
  for (int mf = 0; mf < 2; ++mf)
#pragma unroll
    for (int r = 0; r < 4; ++r)
      sm.outb[m0 + mf * 16 + lk * 4 + r][n0 + l16] = acc2[mf][r] + b2v;
  __syncthreads();

  // coalesced out store: 256B contiguous per row
  {
    const int row = tid >> 3;
    const int q8 = (tid & 7) * 8;
    const f32x4 v0 = *(const f32x4*)(&sm.outb[row][q8]);
    const f32x4 v1 = *(const f32x4*)(&sm.outb[row][q8 + 4]);
    float* op = out + ((size_t)(b0 + row) * A_ + a) * NACT_ + q8;
    *(f32x4*)op = v0;
    *(f32x4*)(op + 4) = v1;
  }
}

extern "C" void kernel_launch(void* const* d_in, const int* in_sizes, int n_in,
                              void* d_out, int out_size, void* d_ws,
                              size_t ws_size, hipStream_t stream) {
  const float* x = (const float*)d_in[0];
  const float* w1 = (const float*)d_in[1];
  const float* b1 = (const float*)d_in[2];
  const float* w2 = (const float*)d_in[3];
  const float* b2 = (const float*)d_in[4];
  const int* routing = (const int*)d_in[5];
  float* out = (float*)d_out;

  char* ws = (char*)d_ws;
  unsigned short* w1t = (unsigned short*)(ws + WS_W1T);
  unsigned short* w2t = (unsigned short*)(ws + WS_W2T);
  float* bias1 = (float*)(ws + WS_B1);
  float* bias2 = (float*)(ws + WS_B2);

  prep_w1<<<A_ * 64, 256, 0, stream>>>(w1, routing, w1t);
  prep_w2<<<A_ * 8, 256, 0, stream>>>(w2, routing, w2t);
  prep_bias<<<A_, 512, 0, stream>>>(w1, b1, b2, routing, bias1, bias2);
  divtree_main<<<A_ * (B_ / BM_), 512, 0, stream>>>(x, w1t, w2t, bias1, bias2,
                                                    out);
}

// Round 4
// 143.170 us; speedup vs baseline: 1.2371x; 1.2371x over previous
//
#include <hip/hip_runtime.h>

typedef __attribute__((ext_vector_type(8))) short bf16x8;
typedef __attribute__((ext_vector_type(4))) float f32x4;
typedef __attribute__((ext_vector_type(4))) unsigned short u16x4;
typedef __attribute__((ext_vector_type(8))) unsigned short u16x8;

#define B_ 2048
#define A_ 50
#define H_ 512
#define NACT_ 64
#define F_ 562
#define BM_ 64
#define BK_ 32
#define NSTEP_ (H_ / BK_) /* 16 */

// ws layout (bytes)
#define WS_W1T 0
#define WS_W2T ((size_t)A_ * H_ * H_ * 2)                    /* 26,214,400 */
#define WS_B1 (WS_W2T + (size_t)A_ * NACT_ * H_ * 2)         /* 29,491,200 */
#define WS_B2 (WS_B1 + (size_t)A_ * H_ * 4)                  /* 29,593,600 */

static __device__ __forceinline__ unsigned short f2bf(float f) {
  unsigned int u = __builtin_bit_cast(unsigned int, f);
  u += 0x7fffu + ((u >> 16) & 1u);
  return (unsigned short)(u >> 16);
}

static __device__ __forceinline__ void gld_lds16(const unsigned short* src,
                                                 unsigned short* dst) {
  __builtin_amdgcn_global_load_lds(
      (const __attribute__((address_space(1))) unsigned int*)(const void*)src,
      (__attribute__((address_space(3))) unsigned int*)(void*)dst, 16, 0, 0);
}

static __device__ __forceinline__ int clamp_r(int r) {
  return r < 0 ? 0 : (r > A_ - 1 ? A_ - 1 : r);
}

// W1T step-tiled + pre-swizzled: value (a,j,k), t=k>>5, sub=(k>>3)&3, elem=k&7
// stored at ((a*16 + t)*512 + j)*32 + (sub ^ (j&3))*8 + elem.
// Phase-2 mapping chosen so 256 consecutive threads store 4 KiB contiguously.
__global__ void prep_w1(const float* __restrict__ w1,
                        const int* __restrict__ routing,
                        unsigned short* __restrict__ w1t) {
  const int bid = blockIdx.x;
  const int a = bid / 64;
  const int tile = bid - a * 64;
  const int tk = tile & 7, tj = tile >> 3;
  const int k0 = tk * 64, j0 = tj * 64;
  const int r = clamp_r(routing[a]);
  __shared__ float tl[64][65];
  const int t = threadIdx.x;
  const int c = t & 63, q = t >> 6;
#pragma unroll
  for (int i = 0; i < 16; ++i) {
    const int kl = q + i * 4;
    tl[kl][c] = w1[((size_t)r * F_ + k0 + kl) * H_ + j0 + c];
  }
  __syncthreads();
  // thread t, slab it: jl=t>>2, c2=t&3, kc=it*4+(c2^(jl&3)); dst contiguous.
#pragma unroll
  for (int it = 0; it < 2; ++it) {
    const int jl = t >> 2, c2 = t & 3;
    const int kc = it * 4 + (c2 ^ (jl & 3));
    u16x8 v;
#pragma unroll
    for (int e = 0; e < 8; ++e) v[e] = f2bf(tl[kc * 8 + e][jl]);
    unsigned short* dst = w1t +
        (((size_t)a * 16 + tk * 2 + it) * H_ + j0 + jl) * 32 + c2 * 8;
    *(u16x8*)dst = v;
  }
}

// W2T[a][n][k] = bf16(W2[r_a][k][n])
__global__ void prep_w2(const float* __restrict__ w2,
                        const int* __restrict__ routing,
                        unsigned short* __restrict__ w2t) {
  const int bid = blockIdx.x;
  const int a = bid >> 3;
  const int tk = bid & 7;
  const int k0 = tk * 64;
  const int r = clamp_r(routing[a]);
  __shared__ float tl[64][65];
  const int t = threadIdx.x;
  const int c = t & 63, q = t >> 6;
#pragma unroll
  for (int i = 0; i < 16; ++i) {
    const int kl = q + i * 4;
    tl[kl][c] = w2[((size_t)r * H_ + k0 + kl) * NACT_ + c];
  }
  __syncthreads();
#pragma unroll
  for (int i = 0; i < 16; ++i) {
    const int nl = q + i * 4;
    w2t[((size_t)a * NACT_ + nl) * H_ + k0 + c] = f2bf(tl[c][nl]);
  }
}

__global__ void prep_bias(const float* __restrict__ w1,
                          const float* __restrict__ b1,
                          const float* __restrict__ b2,
                          const int* __restrict__ routing,
                          float* __restrict__ bias1, float* __restrict__ bias2) {
  const int a = blockIdx.x;
  const int t = threadIdx.x;
  const int r = clamp_r(routing[a]);
  bias1[a * H_ + t] = b1[(size_t)r * H_ + t] + w1[((size_t)r * F_ + H_ + a) * H_ + t];
  if (t < NACT_) bias2[a * NACT_ + t] = b2[r * NACT_ + t];
}

__global__ __launch_bounds__(512, 4) void divtree_main(
    const float* __restrict__ x, const unsigned short* __restrict__ w1t,
    const unsigned short* __restrict__ w2t, const float* __restrict__ bias1,
    const float* __restrict__ bias2, float* __restrict__ out) {
  __shared__ union {
    struct {
      unsigned short w1[2][H_ * BK_];   // 2 x 32 KiB, linear (pre-swizzled)
      unsigned short xs[2][BM_ * BK_];  // 2 x 4 KiB, swizzled rows
    } st;                               // 72 KiB
    unsigned short h[BM_ * H_];         // 64 KiB (after K-loop)
    float outb[BM_][66];                // (after layer 2)
  } sm;

  // XCD-bijective swizzle: 1600 blocks, 1600 % 8 == 0 -> cpx = 200
  const int bid = blockIdx.x;
  const int swz = (bid & 7) * 200 + (bid >> 3);
  const int a = swz >> 5;    // agent (0..49)
  const int mblk = swz & 31; // M tile (0..31)
  const int b0 = mblk * BM_;

  const int tid = threadIdx.x;
  const int lane = tid & 63;
  const int w = tid >> 6; // wave 0..7
  const int l16 = lane & 15;
  const int lk = lane >> 4; // 0..3
  const int sxor = lk ^ (l16 & 3);

  const int wj = w * 64; // layer-1 wave tile: 64(j) x 64(m)

  const unsigned short* w1ta = w1t + (size_t)a * (H_ * H_);

  // X staging: thread -> (row = tid>>3, 4-float chunk xq = tid&7)
  const int xrow = tid >> 3;
  const int xq = tid & 7;
  const float* xbase =
      x + ((size_t)(b0 + xrow) * A_ + (size_t)a) * H_ + (size_t)xq * 4;
  const int xs_off = xrow * BK_ + ((xq >> 1) ^ (xrow & 3)) * 8 + (xq & 1) * 4;

  const int afr_base = (wj + l16) * BK_ + sxor * 8;
  const int bfr_base = l16 * BK_ + sxor * 8;

  f32x4 acc[4][4];
#pragma unroll
  for (int i = 0; i < 4; ++i)
#pragma unroll
    for (int j = 0; j < 4; ++j) acc[i][j] = (f32x4){0.f, 0.f, 0.f, 0.f};

  f32x4 xr[3]; // x(s) lives in xr[s%3]; all indices compile-time (full unroll)

  // ---- prologue: x(0) now; stage(0); issue x(1), x(2) ----
  {
    const f32x4 xv0 = *(const f32x4*)xbase; // x(0)
#pragma unroll
    for (int i = 0; i < 4; ++i)
      gld_lds16(w1ta + ((size_t)(i * 512 + tid) << 3),
                sm.st.w1[0] + (size_t)(i * 512 + (w << 6)) * 8);
    xr[1] = *(const f32x4*)(xbase + 1 * BK_);
    xr[2] = *(const f32x4*)(xbase + 2 * BK_);
    u16x4 v;
#pragma unroll
    for (int e = 0; e < 4; ++e) v[e] = f2bf(xv0[e]);
    *(u16x4*)(sm.st.xs[0] + xs_off) = v;
  }

  // ---- K-loop: one barrier/step, counted vmcnt (never 0 until tail) ----
#pragma unroll
  for (int t = 0; t < NSTEP_; ++t) {
    const int buf = t & 1;
    // wait: gld(t) landed (issued after previous barrier -> full step of
    // latency cover); lgkmcnt(0) makes prev xs ds_write visible.
    if (t <= NSTEP_ - 3)
      asm volatile("s_waitcnt vmcnt(1) lgkmcnt(0)" ::: "memory");
    else
      asm volatile("s_waitcnt vmcnt(0) lgkmcnt(0)" ::: "memory");
    __builtin_amdgcn_sched_barrier(0);
    __builtin_amdgcn_s_barrier();
    __builtin_amdgcn_sched_barrier(0);
    // issue next staging AFTER barrier (all waves done reading buf^1)
    if (t + 1 < NSTEP_) {
      const unsigned short* wsrc = w1ta + (size_t)(t + 1) * (H_ * BK_);
      unsigned short* wdst = sm.st.w1[buf ^ 1];
#pragma unroll
      for (int i = 0; i < 4; ++i)
        gld_lds16(wsrc + ((size_t)(i * 512 + tid) << 3),
                  wdst + (size_t)(i * 512 + (w << 6)) * 8);
    }
    if (t + 3 < NSTEP_)
      xr[(t + 3) % 3] = *(const f32x4*)(xbase + (size_t)(t + 3) * BK_);
    // compute current tile: D[j][m] = W1T(j,k) * x(m,k)^T
    const unsigned short* w1s = sm.st.w1[buf];
    const unsigned short* xss = sm.st.xs[buf];
    bf16x8 bfr[4];
#pragma unroll
    for (int mf = 0; mf < 4; ++mf)
      bfr[mf] = *(const bf16x8*)(xss + bfr_base + mf * (16 * BK_));
    __builtin_amdgcn_s_setprio(1);
#pragma unroll
    for (int jf = 0; jf < 4; ++jf) {
      const bf16x8 afr = *(const bf16x8*)(w1s + afr_base + jf * (16 * BK_));
#pragma unroll
      for (int mf = 0; mf < 4; ++mf)
        acc[jf][mf] = __builtin_amdgcn_mfma_f32_16x16x32_bf16(
            afr, bfr[mf], acc[jf][mf], 0, 0, 0);
    }
    __builtin_amdgcn_s_setprio(0);
    // late conversion + xs write for t+1 (x arrived under the top wait)
    if (t + 1 < NSTEP_) {
      const f32x4 xv = xr[(t + 1) % 3];
      u16x4 v;
#pragma unroll
      for (int e = 0; e < 4; ++e) v[e] = f2bf(xv[e]);
      *(u16x4*)(sm.st.xs[buf ^ 1] + xs_off) = v;
    }
  }
  __syncthreads();

  // h = relu(acc + bias1_eff) -> LDS bf16, XOR-swizzled rows
  const float* b1p = bias1 + a * H_;
#pragma unroll
  for (int jf = 0; jf < 4; ++jf) {
    const f32x4 bv = *(const f32x4*)(b1p + wj + jf * 16 + lk * 4);
    const int cbase = (wj >> 3) + jf * 2 + (lk >> 1);
    const int half4 = (lk & 1) * 4;
#pragma unroll
    for (int mf = 0; mf < 4; ++mf) {
      u16x4 hv;
#pragma unroll
      for (int r = 0; r < 4; ++r) {
        float f = acc[jf][mf][r] + bv[r];
        f = f > 0.f ? f : 0.f;
        hv[r] = f2bf(f);
      }
      const int m = mf * 16 + l16;
      const int off = m * H_ + ((cbase ^ (l16 & 7))) * 8 + half4;
      *(u16x4*)(sm.h + off) = hv;
    }
  }
  __syncthreads();

  // layer 2: out[m][n] = h(m,k) * W2T(n,k)^T ; wave tile 32(m) x 16(n)
  const int m0 = (w & 1) * 32;
  const int n0 = (w >> 1) * 16;
  const unsigned short* w2p =
      w2t + ((size_t)a * NACT_ + n0 + l16) * H_ + lk * 8;
  f32x4 acc2[2];
  acc2[0] = (f32x4){0.f, 0.f, 0.f, 0.f};
  acc2[1] = (f32x4){0.f, 0.f, 0.f, 0.f};
#pragma unroll
  for (int kf = 0; kf < 16; ++kf) {
    const bf16x8 bf2 = *(const bf16x8*)(w2p + kf * 32);
#pragma unroll
    for (int mf = 0; mf < 2; ++mf) {
      const int row = m0 + mf * 16 + l16;
      const int off = row * H_ + (((kf * 4 + lk) ^ (l16 & 7))) * 8;
      const bf16x8 af2 = *(const bf16x8*)(sm.h + off);
      acc2[mf] = __builtin_amdgcn_mfma_f32_16x16x32_bf16(af2, bf2, acc2[mf],
                                                         0, 0, 0);
    }
  }
  const float b2v = bias2[a * NACT_ + n0 + l16];
  __syncthreads(); // h reads done before outb overwrite (aliased)
#pragma unroll
  for (int mf = 0; mf < 2; ++mf)
#pragma unroll
    for (int r = 0; r < 4; ++r)
      sm.outb[m0 + mf * 16 + lk * 4 + r][n0 + l16] = acc2[mf][r] + b2v;
  __syncthreads();

  // coalesced out store: 256B contiguous per row
  {
    const int row = tid >> 3;
    const int q8 = (tid & 7) * 8;
    const f32x4 v0 = *(const f32x4*)(&sm.outb[row][q8]);
    const f32x4 v1 = *(const f32x4*)(&sm.outb[row][q8 + 4]);
    float* op = out + ((size_t)(b0 + row) * A_ + a) * NACT_ + q8;
    *(f32x4*)op = v0;
    *(f32x4*)(op + 4) = v1;
  }
}

extern "C" void kernel_launch(void* const* d_in, const int* in_sizes, int n_in,
                              void* d_out, int out_size, void* d_ws,
                              size_t ws_size, hipStream_t stream) {
  const float* x = (const float*)d_in[0];
  const float* w1 = (const float*)d_in[1];
  const float* b1 = (const float*)d_in[2];
  const float* w2 = (const float*)d_in[3];
  const float* b2 = (const float*)d_in[4];
  const int* routing = (const int*)d_in[5];
  float* out = (float*)d_out;

  char* ws = (char*)d_ws;
  unsigned short* w1t = (unsigned short*)(ws + WS_W1T);
  unsigned short* w2t = (unsigned short*)(ws + WS_W2T);
  float* bias1 = (float*)(ws + WS_B1);
  float* bias2 = (float*)(ws + WS_B2);

  prep_w1<<<A_ * 64, 256, 0, stream>>>(w1, routing, w1t);
  prep_w2<<<A_ * 8, 256, 0, stream>>>(w2, routing, w2t);
  prep_bias<<<A_, 512, 0, stream>>>(w1, b1, b2, routing, bias1, bias2);
  divtree_main<<<A_ * (B_ / BM_), 512, 0, stream>>>(x, w1t, w2t, bias1, bias2,
                                                    out);
}